// Round 2
// baseline (1057.280 us; speedup 1.0000x reference)
//
#include <hip/hip_runtime.h>
#include <stdint.h>

#define NPED 256   // agents
#define DH   128   // hidden dim
#define NEMB 64    // embedding dim
#define NG   64    // grid cells (8x8)
#define TOBS 8
#define TPRED 12

// ---------- JAX-compatible Threefry2x32 ----------
__device__ __forceinline__ uint32_t rotl32(uint32_t v, int n) {
  return (v << n) | (v >> (32 - n));
}

__device__ __forceinline__ void threefry2x32(uint32_t k0, uint32_t k1,
                                             uint32_t x0, uint32_t x1,
                                             uint32_t& o0, uint32_t& o1) {
  uint32_t ks2 = k0 ^ k1 ^ 0x1BD11BDAu;
  x0 += k0; x1 += k1;
  x0 += x1; x1 = rotl32(x1, 13); x1 ^= x0;
  x0 += x1; x1 = rotl32(x1, 15); x1 ^= x0;
  x0 += x1; x1 = rotl32(x1, 26); x1 ^= x0;
  x0 += x1; x1 = rotl32(x1,  6); x1 ^= x0;
  x0 += k1; x1 += ks2 + 1u;
  x0 += x1; x1 = rotl32(x1, 17); x1 ^= x0;
  x0 += x1; x1 = rotl32(x1, 29); x1 ^= x0;
  x0 += x1; x1 = rotl32(x1, 16); x1 ^= x0;
  x0 += x1; x1 = rotl32(x1, 24); x1 ^= x0;
  x0 += ks2; x1 += k0 + 2u;
  x0 += x1; x1 = rotl32(x1, 13); x1 ^= x0;
  x0 += x1; x1 = rotl32(x1, 15); x1 ^= x0;
  x0 += x1; x1 = rotl32(x1, 26); x1 ^= x0;
  x0 += x1; x1 = rotl32(x1,  6); x1 ^= x0;
  x0 += k0; x1 += k1 + 3u;
  x0 += x1; x1 = rotl32(x1, 17); x1 ^= x0;
  x0 += x1; x1 = rotl32(x1, 29); x1 ^= x0;
  x0 += x1; x1 = rotl32(x1, 16); x1 ^= x0;
  x0 += x1; x1 = rotl32(x1, 24); x1 ^= x0;
  x0 += k1; x1 += ks2 + 4u;
  x0 += x1; x1 = rotl32(x1, 13); x1 ^= x0;
  x0 += x1; x1 = rotl32(x1, 15); x1 ^= x0;
  x0 += x1; x1 = rotl32(x1, 26); x1 ^= x0;
  x0 += x1; x1 = rotl32(x1,  6); x1 ^= x0;
  x0 += ks2; x1 += k0 + 5u;
  o0 = x0; o1 = x1;
}

// ---------- XLA-matched f32 special functions (no FMA contraction) ----------
// XLA/Eigen rational tanh (elemental_ir_emitter EmitTanh / Eigen ptanh<float>)
__device__ __forceinline__ float tanh_xla(float x) {
  const float kMax = 7.90531110763549805f;
  float ax = fabsf(x);
  float xc = fminf(fmaxf(x, -kMax), kMax);
  float x2 = __fmul_rn(xc, xc);
  float p = -2.76076847742355e-16f;
  p = __fadd_rn(__fmul_rn(p, x2), 2.00018790482477e-13f);
  p = __fadd_rn(__fmul_rn(p, x2), -8.60467152213735e-10f);
  p = __fadd_rn(__fmul_rn(p, x2), 5.12229709037114e-08f);
  p = __fadd_rn(__fmul_rn(p, x2), 1.48572235717979e-05f);
  p = __fadd_rn(__fmul_rn(p, x2), 6.37261928875436e-04f);
  p = __fadd_rn(__fmul_rn(p, x2), 4.89352455891786e-03f);
  float num = __fmul_rn(xc, p);
  float q = 1.19825839466702e-06f;
  q = __fadd_rn(__fmul_rn(q, x2), 1.18534705686654e-04f);
  q = __fadd_rn(__fmul_rn(q, x2), 2.26843463243900e-03f);
  q = __fadd_rn(__fmul_rn(q, x2), 4.89352518554385e-03f);
  float r = __fdiv_rn(num, q);
  return (ax < 0.0004f) ? x : r;
}

// XLA LogisticExpander: sigmoid(x) = 0.5 + 0.5*tanh(0.5*x)
__device__ __forceinline__ float sigmoid_xla(float x) {
  return __fadd_rn(0.5f, __fmul_rn(0.5f, tanh_xla(__fmul_rn(0.5f, x))));
}

// XLA EmitLog1p: u = x+1; (u==1) ? x : log(u)*x/(u-1)
__device__ __forceinline__ float log1p_xla(float x) {
  float u = __fadd_rn(x, 1.0f);
  if (u == 1.0f) return x;
  return __fmul_rn(logf(u), __fdiv_rn(x, __fsub_rn(u, 1.0f)));
}

// XLA ErfInv32 (Giles polynomial)
__device__ __forceinline__ float erfinv_xla(float x) {
  float nx2 = -__fmul_rn(x, x);
  float w = -log1p_xla(nx2);
  float p;
  if (w < 5.0f) {
    w = __fsub_rn(w, 2.5f);
    p = 2.81022636e-08f;
    p = __fadd_rn(__fmul_rn(p, w), 3.43273939e-07f);
    p = __fadd_rn(__fmul_rn(p, w), -3.5233877e-06f);
    p = __fadd_rn(__fmul_rn(p, w), -4.39150654e-06f);
    p = __fadd_rn(__fmul_rn(p, w), 0.00021858087f);
    p = __fadd_rn(__fmul_rn(p, w), -0.00125372503f);
    p = __fadd_rn(__fmul_rn(p, w), -0.00417768164f);
    p = __fadd_rn(__fmul_rn(p, w), 0.246640727f);
    p = __fadd_rn(__fmul_rn(p, w), 1.50140941f);
  } else {
    w = __fsub_rn(__fsqrt_rn(w), 3.0f);
    p = -0.000200214257f;
    p = __fadd_rn(__fmul_rn(p, w), 0.000100950558f);
    p = __fadd_rn(__fmul_rn(p, w), 0.00134934322f);
    p = __fadd_rn(__fmul_rn(p, w), -0.00367342844f);
    p = __fadd_rn(__fmul_rn(p, w), 0.00573950773f);
    p = __fadd_rn(__fmul_rn(p, w), -0.0076224613f);
    p = __fadd_rn(__fmul_rn(p, w), 0.00943887047f);
    p = __fadd_rn(__fmul_rn(p, w), 1.00167406f);
    p = __fadd_rn(__fmul_rn(p, w), 2.83297682f);
  }
  return __fmul_rn(p, x);
}

// jax uniform(-1+ulp,1) -> sqrt(2)*erfinv(u); input is the partitionable bits word
__device__ __forceinline__ float bits_to_normal(uint32_t b) {
  uint32_t fb = (b >> 9) | 0x3f800000u;
  float f = __fsub_rn(__uint_as_float(fb), 1.0f);   // [0,1)
  const float lo = -0.99999994f;                    // nextafter(-1,0) in f32
  float u = __fadd_rn(__fmul_rn(f, 2.0f), lo);      // (maxval-minval) == 2.0f exactly
  u = fmaxf(lo, u);
  return __fmul_rn(1.41421354f, erfinv_xla(u));     // f32(sqrt(2)) * erfinv
}

// ---------- K1: HW batched GEMM + (positions / noise / o-projection) ----------
// grid = 257 blocks x 256 threads.  Blocks 0..255: HW[j,g,e] = sum_d h[j,d]*Wa[g*128+d,e].
// Block 256: if t<8 copy positions from input; else o = h@Wp+bp, store prev o to out,
// partitionable-Threefry noise, position update.
__global__ __launch_bounds__(256) void k_hw(
    const float* __restrict__ x_input, const float* __restrict__ Wa,
    const float* __restrict__ Wp, const float* __restrict__ bp,
    const float* __restrict__ h, float* __restrict__ pos,
    float* __restrict__ HW, float* __restrict__ out, int t) {
  __shared__ float hl[64][129];
  __shared__ float wl[128][65];
  const int w = blockIdx.x;
  const int tid = threadIdx.x;

  if (w == 256) {
    if (t < TOBS) {
      pos[tid * 2 + 0] = x_input[(t * NPED + tid) * 3 + 1];
      pos[tid * 2 + 1] = x_input[(t * NPED + tid) * 3 + 2];
    } else {
      // folded key = threefry2x32((0,42), (0, t-8))
      uint32_t fk0, fk1;
      threefry2x32(0u, 42u, 0u, (uint32_t)(t - TOBS), fk0, fk1);
      // partitionable random_bits: elem m -> xor of the two output words of
      // threefry2x32(fk, hi(m)=0, lo(m)=m); z[i,0]=elem 2i, z[i,1]=elem 2i+1
      uint32_t p0, p1, q0, q1;
      threefry2x32(fk0, fk1, 0u, (uint32_t)(2 * tid),     p0, p1);
      threefry2x32(fk0, fk1, 0u, (uint32_t)(2 * tid + 1), q0, q1);
      float z0 = bits_to_normal(p0 ^ p1);
      float z1 = bits_to_normal(q0 ^ q1);
      // o(t-1) = h @ Wp + bp  (h currently holds the post-step hidden)
      const int i = tid;
      float a0 = bp[0], a1 = bp[1], a2 = bp[2], a3 = bp[3], a4 = bp[4];
      for (int d = 0; d < DH; ++d) {
        float hv = h[i * DH + d];
        a0 = fmaf(hv, Wp[d * 5 + 0], a0);
        a1 = fmaf(hv, Wp[d * 5 + 1], a1);
        a2 = fmaf(hv, Wp[d * 5 + 2], a2);
        a3 = fmaf(hv, Wp[d * 5 + 3], a3);
        a4 = fmaf(hv, Wp[d * 5 + 4], a4);
      }
      if (t >= TOBS + 1) {   // o(t-1) is pred output row t-9
        float* op = out + ((t - TOBS - 1) * NPED + i) * 5;
        op[0] = a0; op[1] = a1; op[2] = a2; op[3] = a3; op[4] = a4;
      }
      // position sampling (uncontracted, XLA op order)
      float sx = expf(a2), sy = expf(a3), r = tanh_xla(a4);
      float px = __fadd_rn(a0, __fmul_rn(sx, z0));
      float s1mr2 = __fsqrt_rn(__fsub_rn(1.0f, __fmul_rn(r, r)));
      float inner = __fadd_rn(__fmul_rn(r, z0), __fmul_rn(s1mr2, z1));
      float py = __fadd_rn(a1, __fmul_rn(sy, inner));
      pos[i * 2 + 0] = px;
      pos[i * 2 + 1] = py;
    }
    return;
  }

  // ---- HW GEMM: block (g, j-tile) ----
  const int g  = w >> 2;
  const int jt = (w & 3) * 64;
  for (int idx = tid; idx < 64 * DH; idx += 256) {
    int r = idx >> 7, d2 = idx & 127;
    hl[r][d2] = h[(jt + r) * DH + d2];
  }
  for (int idx = tid; idx < DH * 64; idx += 256) {
    int r = idx >> 6, e2 = idx & 63;
    wl[r][e2] = Wa[(g * DH + r) * 64 + e2];
  }
  __syncthreads();
  const int jl = (tid >> 4) << 2;
  const int el = (tid & 15) << 2;
  float acc[4][4];
#pragma unroll
  for (int a = 0; a < 4; ++a)
#pragma unroll
    for (int b = 0; b < 4; ++b) acc[a][b] = 0.0f;
  for (int d = 0; d < DH; ++d) {
    float av[4], bv[4];
#pragma unroll
    for (int a = 0; a < 4; ++a) av[a] = hl[jl + a][d];
#pragma unroll
    for (int b = 0; b < 4; ++b) bv[b] = wl[d][el + b];
#pragma unroll
    for (int a = 0; a < 4; ++a)
#pragma unroll
      for (int b = 0; b < 4; ++b) acc[a][b] = fmaf(av[a], bv[b], acc[a][b]);
  }
#pragma unroll
  for (int a = 0; a < 4; ++a) {
    int j = jt + jl + a;
    float* dst = HW + (j * NG + g) * 64 + el;
#pragma unroll
    for (int b = 0; b < 4; ++b) dst[b] = acc[a][b];
  }
}

// ---------- K2: cells + gather a[i] + emb assembly ----------
// grid = 256 blocks (one per agent i) x 256 threads.
// emb row layout: [ e(0:64) | a(64:128) | h(128:256) ]
__global__ __launch_bounds__(256) void k_gather(
    const float* __restrict__ We, const float* __restrict__ be,
    const float* __restrict__ ba, const float* __restrict__ pos,
    const float* __restrict__ h, const float* __restrict__ HW,
    float* __restrict__ emb) {
  const int i = blockIdx.x;
  const int tid = threadIdx.x;
  __shared__ unsigned char cg[NPED];
  __shared__ float red[4][NEMB];
  const float pix = pos[i * 2 + 0], piy = pos[i * 2 + 1];
  {
    const int j = tid;
    float rx = __fsub_rn(pos[j * 2 + 0], pix);   // rel = pos[j] - pos[i]
    float ry = __fsub_rn(pos[j * 2 + 1], piy);
    float cx = floorf(__fmul_rn(__fadd_rn(rx, 2.0f), 2.0f));  // (rel+half)/0.5
    float cy = floorf(__fmul_rn(__fadd_rn(ry, 2.0f), 2.0f));
    unsigned char v = 255;
    if (cx >= 0.0f && cx < 8.0f && cy >= 0.0f && cy < 8.0f && j != i)
      v = (unsigned char)((int)cx * 8 + (int)cy);
    cg[j] = v;
  }
  __syncthreads();
  const int e = tid & 63;
  const int q = tid >> 6;
  float acc = 0.0f;
#pragma unroll 4
  for (int jj = 0; jj < 64; ++jj) {
    int j = (q << 6) + jj;          // same j across the wave -> cg broadcast
    int gidx = cg[j];
    if (gidx != 255) acc = __fadd_rn(acc, HW[(j * NG + gidx) * 64 + e]);
  }
  red[q][e] = acc;
  __syncthreads();
  if (q == 0) {
    float s = __fadd_rn(__fadd_rn(__fadd_rn(red[0][e], red[1][e]),
                                  __fadd_rn(red[2][e], red[3][e])), ba[e]);
    emb[i * 256 + NEMB + e] = fmaxf(s, 0.0f);
  } else if (q == 1) {
    float v = __fadd_rn(__fadd_rn(__fmul_rn(pix, We[e]),
                                  __fmul_rn(piy, We[NEMB + e])), be[e]);
    emb[i * 256 + e] = fmaxf(v, 0.0f);
  } else {
    int d = ((q - 2) << 6) + e;
    emb[i * 256 + 128 + d] = h[i * DH + d];
  }
}

// ---------- K3: z = emb@Wl + h@Ul + b, LSTM pointwise ----------
// grid = 64 blocks: (i-tile of 16) x (d-slice of 32, all 4 gates). 256 threads.
__global__ __launch_bounds__(256) void k_lstm(
    const float* __restrict__ Wl, const float* __restrict__ Ul,
    const float* __restrict__ bl, const float* __restrict__ emb,
    float* __restrict__ h, float* __restrict__ c) {
  const int wg = blockIdx.x;
  const int i0 = (wg >> 2) << 4;
  const int d0 = (wg & 3) << 5;
  const int tid = threadIdx.x;
  __shared__ float A[16][257];
  __shared__ float W[32][129];
  for (int r = 0; r < 16; ++r) A[r][tid] = emb[(i0 + r) * 256 + tid];
  const int dd = tid & 31;
  const int ip = tid >> 5;
  const int lc = tid & 127;
  const int col = ((lc >> 5) << 7) + d0 + (lc & 31);  // gate*128 + d0 + dd
  const int rbase = tid >> 7;
  // separate accumulators for emb@Wl (k<128) and h@Ul (k>=128), matching
  // XLA's (dot1 + dot2) + b rounding structure
  float accW0[4] = {0,0,0,0}, accW1[4] = {0,0,0,0};
  float accU0[4] = {0,0,0,0}, accU1[4] = {0,0,0,0};
  for (int kc = 0; kc < 8; ++kc) {
    __syncthreads();
    for (int r2 = rbase; r2 < 32; r2 += 2) {
      int k = (kc << 5) + r2;
      W[r2][lc] = (k < 128) ? Wl[k * 512 + col] : Ul[(k - 128) * 512 + col];
    }
    __syncthreads();
    float* a0p = (kc < 4) ? accW0 : accU0;
    float* a1p = (kc < 4) ? accW1 : accU1;
#pragma unroll
    for (int kk = 0; kk < 32; ++kk) {
      float a0 = A[ip * 2 + 0][(kc << 5) + kk];
      float a1 = A[ip * 2 + 1][(kc << 5) + kk];
#pragma unroll
      for (int gt = 0; gt < 4; ++gt) {
        float wv = W[kk][(gt << 5) + dd];
        a0p[gt] = fmaf(a0, wv, a0p[gt]);
        a1p[gt] = fmaf(a1, wv, a1p[gt]);
      }
    }
  }
  const int d = d0 + dd;
#pragma unroll
  for (int p = 0; p < 2; ++p) {
    float* aW = p ? accW1 : accW0;
    float* aU = p ? accU1 : accU0;
    int i = i0 + ip * 2 + p;
    float zi = __fadd_rn(__fadd_rn(aW[0], aU[0]), bl[0 * DH + d]);
    float zf = __fadd_rn(__fadd_rn(aW[1], aU[1]), bl[1 * DH + d]);
    float zg = __fadd_rn(__fadd_rn(aW[2], aU[2]), bl[2 * DH + d]);
    float zo = __fadd_rn(__fadd_rn(aW[3], aU[3]), bl[3 * DH + d]);
    float cold = c[i * DH + d];
    float cn = __fadd_rn(__fmul_rn(sigmoid_xla(zf), cold),
                         __fmul_rn(sigmoid_xla(zi), tanh_xla(zg)));
    float hn = __fmul_rn(sigmoid_xla(zo), tanh_xla(cn));
    c[i * DH + d] = cn;
    h[i * DH + d] = hn;
  }
}

// ---------- Final: o(19) -> out row 11 ----------
__global__ __launch_bounds__(256) void k_out_final(
    const float* __restrict__ Wp, const float* __restrict__ bp,
    const float* __restrict__ h, float* __restrict__ out) {
  const int i = threadIdx.x;
  float a0 = bp[0], a1 = bp[1], a2 = bp[2], a3 = bp[3], a4 = bp[4];
  for (int d = 0; d < DH; ++d) {
    float hv = h[i * DH + d];
    a0 = fmaf(hv, Wp[d * 5 + 0], a0);
    a1 = fmaf(hv, Wp[d * 5 + 1], a1);
    a2 = fmaf(hv, Wp[d * 5 + 2], a2);
    a3 = fmaf(hv, Wp[d * 5 + 3], a3);
    a4 = fmaf(hv, Wp[d * 5 + 4], a4);
  }
  float* op = out + ((TPRED - 1) * NPED + i) * 5;
  op[0] = a0; op[1] = a1; op[2] = a2; op[3] = a3; op[4] = a4;
}

extern "C" void kernel_launch(void* const* d_in, const int* in_sizes, int n_in,
                              void* d_out, int out_size, void* d_ws, size_t ws_size,
                              hipStream_t stream) {
  const float* x_input = (const float*)d_in[0];
  const float* We = (const float*)d_in[1];
  const float* be = (const float*)d_in[2];
  const float* Wa = (const float*)d_in[3];
  const float* ba = (const float*)d_in[4];
  const float* Wl = (const float*)d_in[5];
  const float* Ul = (const float*)d_in[6];
  const float* bl = (const float*)d_in[7];
  const float* Wp = (const float*)d_in[8];
  const float* bp = (const float*)d_in[9];
  float* out = (float*)d_out;
  float* ws = (float*)d_ws;

  float* h   = ws;                 // 256*128
  float* c   = ws + 32768;         // 256*128
  float* emb = ws + 65536;         // 256*256
  float* pos = ws + 131072;        // 256*2
  float* HW  = ws + 131584;        // 256*64*64 = 4 MB

  hipMemsetAsync(h, 0, (size_t)2 * NPED * DH * sizeof(float), stream);

  for (int t = 0; t < TOBS + TPRED; ++t) {
    k_hw<<<257, 256, 0, stream>>>(x_input, Wa, Wp, bp, h, pos, HW, out, t);
    k_gather<<<256, 256, 0, stream>>>(We, be, ba, pos, h, HW, emb);
    k_lstm<<<64, 256, 0, stream>>>(Wl, Ul, bl, emb, h, c);
  }
  k_out_final<<<1, 256, 0, stream>>>(Wp, bp, h, out);
}